// Round 6
// baseline (230.930 us; speedup 1.0000x reference)
//
#include <hip/hip_runtime.h>
#include <hip/hip_bf16.h>

#define DEV __device__ __forceinline__

typedef __attribute__((ext_vector_type(8))) short short8;
typedef __attribute__((ext_vector_type(4))) float f32x4;

#define MFMA16(a, b, c) __builtin_amdgcn_mfma_f32_16x16x32_bf16((a), (b), (c), 0, 0, 0)

static constexpr int B_ = 2, S_ = 2048, D_ = 1024, H_ = 16, HD_ = 64;
static constexpr long NX = (long)B_ * S_ * D_;   // 4194304
static constexpr long NW = (long)D_ * D_;        // 1048576

DEV short f2bf(float f) {
    __hip_bfloat16 h = __float2bfloat16(f);
    union { __hip_bfloat16 hh; short s; } u;
    u.hh = h;
    return u.s;
}

DEV float bf2f(short s) {
    union { float f; unsigned u; } x;
    x.u = ((unsigned)(unsigned short)s) << 16;
    return x.f;
}

DEV short8 ld8(const short* p) { return *(const short8*)p; }

// async global->LDS, 16B per lane. LDS dest = wave-uniform base + lane*16.
DEV void gld16(const short* g, short* l) {
    __builtin_amdgcn_global_load_lds(
        (const __attribute__((address_space(1))) unsigned int*)g,
        (__attribute__((address_space(3))) unsigned int*)l, 16, 0, 0);
}

// ---------------------------------------------------------------- convert
__global__ __launch_bounds__(256) void convert_all(
    const float* __restrict__ q, const float* __restrict__ k, const float* __restrict__ v,
    const float* __restrict__ wq, const float* __restrict__ wk, const float* __restrict__ wv,
    short* __restrict__ qb, short* __restrict__ kb, short* __restrict__ vb,
    short* __restrict__ wqb, short* __restrict__ wkb, short* __restrict__ wvb) {
    long tid = (long)blockIdx.x * 256 + threadIdx.x;
    long e = tid * 4;
    const float* src; short* dst; long off;
    if      (e < NX)            { src = q;  dst = qb;  off = e; }
    else if (e < 2*NX)          { src = k;  dst = kb;  off = e - NX; }
    else if (e < 3*NX)          { src = v;  dst = vb;  off = e - 2*NX; }
    else if (e < 3*NX + NW)     { src = wq; dst = wqb; off = e - 3*NX; }
    else if (e < 3*NX + 2*NW)   { src = wk; dst = wkb; off = e - 3*NX - NW; }
    else                        { src = wv; dst = wvb; off = e - 3*NX - 2*NW; }
    float4 f = *(const float4*)(src + off);
    short4 o;
    o.x = f2bf(f.x); o.y = f2bf(f.y); o.z = f2bf(f.z); o.w = f2bf(f.w);
    *(short4*)(dst + off) = o;
}

// ---------------------------------------------------------------- GEMM
// m97 recipe + single-barrier async prefetch double-buffer.
__global__ __launch_bounds__(256) void gemm_bias_relu(
    const short* __restrict__ X0, const short* __restrict__ X1, const short* __restrict__ X2,
    const short* __restrict__ W0, const short* __restrict__ W1, const short* __restrict__ W2,
    const float* __restrict__ b0, const float* __restrict__ b1, const float* __restrict__ b2,
    short* __restrict__ O0, short* __restrict__ O1, short* __restrict__ O2) {
    __shared__ short As[2][128 * 32];
    __shared__ short Bs[2][128 * 32];

    const int z = blockIdx.z;
    const short* X   = (z == 0) ? X0 : (z == 1) ? X1 : X2;
    const short* W   = (z == 0) ? W0 : (z == 1) ? W1 : W2;
    const float* bia = (z == 0) ? b0 : (z == 1) ? b1 : b2;
    short*       Out = (z == 0) ? O0 : (z == 1) ? O1 : O2;

    const int tid  = threadIdx.x;
    const int wid  = tid >> 6;
    const int lane = tid & 63;
    const int id   = lane & 15;
    const int quad = lane >> 4;
    const int m0 = blockIdx.y * 128;
    const int n0 = blockIdx.x * 128;
    const int wm = (wid >> 1) * 64;
    const int wn = (wid & 1) * 64;

    const short* Ag0 = X + (long)(m0 + wid * 32 + (lane >> 2)) * D_ + (lane & 3) * 8;
    const short* Bg0 = W + (long)(n0 + wid * 32 + (lane >> 2)) * D_ + (lane & 3) * 8;
    const int offW = wid * 1024;  // wave's 32-row slab

    f32x4 acc[4][4] = {};

    // prologue: stage k-chunk 0 into buf 0
    gld16(Ag0,            &As[0][offW]);
    gld16(Ag0 + 16 * D_,  &As[0][offW + 512]);
    gld16(Bg0,            &Bs[0][offW]);
    gld16(Bg0 + 16 * D_,  &Bs[0][offW + 512]);

    for (int kk = 0; kk < D_; kk += 32) {
        const int cur = (kk >> 5) & 1;
        __syncthreads();  // drains stage(kk) (issued one full compute earlier)
        if (kk + 32 < D_) {
            const int nxt = cur ^ 1;
            gld16(Ag0 + kk + 32,            &As[nxt][offW]);
            gld16(Ag0 + 16 * D_ + kk + 32,  &As[nxt][offW + 512]);
            gld16(Bg0 + kk + 32,            &Bs[nxt][offW]);
            gld16(Bg0 + 16 * D_ + kk + 32,  &Bs[nxt][offW + 512]);
        }

        short8 af[4], bf[4];
#pragma unroll
        for (int i = 0; i < 4; i++) af[i] = ld8(&As[cur][(wm + 16*i + id) * 32 + quad * 8]);
#pragma unroll
        for (int j = 0; j < 4; j++) bf[j] = ld8(&Bs[cur][(wn + 16*j + id) * 32 + quad * 8]);
#pragma unroll
        for (int i = 0; i < 4; i++)
#pragma unroll
            for (int j = 0; j < 4; j++)
                acc[i][j] = MFMA16(af[i], bf[j], acc[i][j]);
    }

#pragma unroll
    for (int j = 0; j < 4; j++) {
        int col = n0 + wn + 16*j + id;
        float bj = bia[col];
#pragma unroll
        for (int i = 0; i < 4; i++) {
#pragma unroll
            for (int r = 0; r < 4; r++) {
                int row = m0 + wm + 16*i + quad*4 + r;
                float val = fmaxf(acc[i][j][r] + bj, 0.f);
                Out[(long)row * D_ + col] = f2bf(val);
            }
        }
    }
}

// ---------------------------------------------------------------- V transpose
// Swizzled LDS tile: elem (row,e) at row*64 + (((e>>3) ^ ((row>>3)&7))*8) + (e&7).
__global__ __launch_bounds__(256) void transpose_v(const short* __restrict__ Vp,
                                                   short* __restrict__ VT) {
    __shared__ short tile[64 * 64];
    const int bh = blockIdx.y;
    const int b = bh >> 4, h = bh & 15;
    const int s0 = blockIdx.x * 64;
    const int t = threadIdx.x;
#pragma unroll
    for (int it = 0; it < 2; it++) {
        int row = (t >> 3) + 32 * it;
        int u   = t & 7;
        short8 d = ld8(Vp + (long)(b * S_ + s0 + row) * D_ + h * HD_ + u * 8);
        *(short8*)(&tile[row * 64 + (u ^ ((row >> 3) & 7)) * 8]) = d;
    }
    __syncthreads();
#pragma unroll
    for (int it = 0; it < 2; it++) {
        int e  = (t >> 3) + 32 * it;
        int sb = (t & 7) * 8;
        short8 o;
#pragma unroll
        for (int u = 0; u < 8; u++) {
            int row = sb + u;
            o[u] = tile[row * 64 + (((e >> 3) ^ ((row >> 3) & 7)) * 8) + (e & 7)];
        }
        *(short8*)(VT + ((long)bh * HD_ + e) * S_ + s0 + sb) = o;
    }
}

// ---------------------------------------------------------------- attention
// 2-wave blocks; 64 queries/wave (4 groups of 16) -> K/V LDS fragment reads
// amortized over 4x MFMAs. K/V frags preloaded to registers once per chunk,
// reused by all groups. Staged via global_load_lds + async prefetch dbuf.
// No online max (scores = relu.relu/8 bounded; masked query -> qf=0).
__global__ __launch_bounds__(128, 2) void attention(
    const short* __restrict__ Qb, const short* __restrict__ Kb,
    const short* __restrict__ VT, const int* __restrict__ mask,
    const float* __restrict__ queries, float* __restrict__ out) {
    __shared__ short Ks[2][64 * 64];        // [buf][key][dim], swizzled units
    __shared__ short Vs[2][64 * 64];        // [buf][dim][key], swizzled units
    __shared__ short pl[2][2][16 * 72];     // [wave][pingpong][16 q][72]

    const int tid  = threadIdx.x;
    const int wid  = tid >> 6;              // 0..1
    const int lane = tid & 63;
    const int id   = lane & 15;
    const int quad = lane >> 4;

    const int bid = blockIdx.x;             // 512 = 16 qb x 16 h x 2 b
    const int qb_ = bid & 15;
    const int h   = (bid >> 4) & 15;
    const int b   = bid >> 8;
    const int q0  = qb_ * 128 + wid * 64;   // wave covers 64 queries

    // Q fragments (B-operand), 4 groups, pre-scaled by 1/8 (0 if masked)
    short8 qf[4][2];
#pragma unroll
    for (int g = 0; g < 4; g++) {
        const short* qbase = Qb + (long)(b * S_ + q0 + g * 16 + id) * D_ + h * HD_ + quad * 8;
        short8 f0 = ld8(qbase);
        short8 f1 = ld8(qbase + 32);
        const float qsc = mask[b * S_ + q0 + g * 16 + id] ? 0.125f : 0.f;
#pragma unroll
        for (int i = 0; i < 8; i++) {
            f0[i] = f2bf(bf2f(f0[i]) * qsc);
            f1[i] = f2bf(bf2f(f1[i]) * qsc);
        }
        qf[g][0] = f0; qf[g][1] = f1;
    }

    // staging: wave wid stages rows [wid*32, wid*32+32) of the 64-row tile,
    // 4 gld16 each for K and V. unit u = (lane&7) ^ (srow&7); (srow+8m)&7==srow&7.
    const int srow = wid * 32 + (lane >> 3);
    const int su   = (lane & 7) ^ (srow & 7);
    const short* kg0 = Kb + ((long)b * S_ + srow) * D_ + h * HD_ + su * 8;
    const short* vg0 = VT + (((long)(b * H_ + h) * HD_) + srow) * S_ + su * 8;

    const int swz = id & 7;  // reader-side swizzle key

    f32x4 l4 = {0.f, 0.f, 0.f, 0.f};  // l partial per group (component g)... no:
    // l partials: per group scalar accum built from per-lane sums
    float lg[4] = {0.f, 0.f, 0.f, 0.f};
    f32x4 o[4][4] = {};

    // prologue: stage chunk 0 into buf 0
#pragma unroll
    for (int m = 0; m < 4; m++) {
        gld16(kg0 + (long)(8 * m) * D_, &Ks[0][wid * 2048 + m * 512]);
        gld16(vg0 + (long)(8 * m) * S_, &Vs[0][wid * 2048 + m * 512]);
    }

    for (int c0 = 0; c0 < S_; c0 += 64) {
        const int cur = (c0 >> 6) & 1;
        __syncthreads();  // drains stage(c0), issued one full chunk earlier
        if (c0 + 64 < S_) {
            const int nxt = cur ^ 1;
            const long cg = (long)(c0 + 64);
#pragma unroll
            for (int m = 0; m < 4; m++) {
                gld16(kg0 + (cg + 8 * m) * D_, &Ks[nxt][wid * 2048 + m * 512]);
                gld16(vg0 + cg + (long)(8 * m) * S_, &Vs[nxt][wid * 2048 + m * 512]);
            }
        }

        // ---- preload K/V fragments once, reuse across 4 query groups
        short8 ka[4][2], va[4][2];
#pragma unroll
        for (int t = 0; t < 4; t++) {
            ka[t][0] = ld8(&Ks[cur][(16*t + id) * 64 + ((quad    ) ^ swz) * 8]);
            ka[t][1] = ld8(&Ks[cur][(16*t + id) * 64 + ((quad ^ 4) ^ swz) * 8]);
        }
#pragma unroll
        for (int j2 = 0; j2 < 4; j2++) {
            va[j2][0] = ld8(&Vs[cur][(16*j2 + id) * 64 + ((quad    ) ^ swz) * 8]);
            va[j2][1] = ld8(&Vs[cur][(16*j2 + id) * 64 + ((quad ^ 4) ^ swz) * 8]);
        }

#pragma unroll
        for (int g = 0; g < 4; g++) {
            // ---- S^T = K·Q^T for this group
            f32x4 s[4];
#pragma unroll
            for (int t = 0; t < 4; t++) s[t] = (f32x4){0.f, 0.f, 0.f, 0.f};
#pragma unroll
            for (int t = 0; t < 4; t++) {
                s[t] = MFMA16(ka[t][0], qf[g][0], s[t]);
                s[t] = MFMA16(ka[t][1], qf[g][1], s[t]);
            }

            // ---- p = exp(s), accumulate l, pack P^T (ping-pong buffer)
            short* plg = &pl[wid][g & 1][0];
            float ls = 0.f;
#pragma unroll
            for (int t = 0; t < 4; t++) {
                float p0 = __expf(s[t][0]);
                float p1 = __expf(s[t][1]);
                float p2 = __expf(s[t][2]);
                float p3 = __expf(s[t][3]);
                ls += (p0 + p1) + (p2 + p3);
                short4 w4;
                w4.x = f2bf(p0); w4.y = f2bf(p1); w4.z = f2bf(p2); w4.w = f2bf(p3);
                *(short4*)(&plg[id * 72 + 16 * t + quad * 4]) = w4;
            }
            lg[g] += ls;
            short8 pf0 = ld8(&plg[id * 72 + quad * 8]);
            short8 pf1 = ld8(&plg[id * 72 + 32 + quad * 8]);

            // ---- O^T += V^T·P^T
#pragma unroll
            for (int j2 = 0; j2 < 4; j2++) {
                o[g][j2] = MFMA16(va[j2][0], pf0, o[g][j2]);
                o[g][j2] = MFMA16(va[j2][1], pf1, o[g][j2]);
            }
        }
    }

    // ---- epilogue
    const long obase = (long)b * (S_ * D_) + (long)h * (HD_ * S_);
#pragma unroll
    for (int g = 0; g < 4; g++) {
        float l = lg[g];
        l += __shfl_xor(l, 16);
        l += __shfl_xor(l, 32);
        const float linv = 1.f / l;
#pragma unroll
        for (int j2 = 0; j2 < 4; j2++) {
#pragma unroll
            for (int r = 0; r < 4; r++) {
                int dim = 16 * j2 + quad * 4 + r;
                long idx = obase + (long)dim * S_ + q0 + g * 16 + id;
                out[idx] = o[g][j2][r] * linv + queries[idx];
            }
        }
    }
}

// ---------------------------------------------------------------- launch
extern "C" void kernel_launch(void* const* d_in, const int* in_sizes, int n_in,
                              void* d_out, int out_size, void* d_ws, size_t ws_size,
                              hipStream_t stream) {
    const float* queries = (const float*)d_in[0];
    const float* keys    = (const float*)d_in[1];
    const float* values  = (const float*)d_in[2];
    const int*   mask    = (const int*)d_in[3];
    const float* Wq = (const float*)d_in[4];
    const float* bq = (const float*)d_in[5];
    const float* Wk = (const float*)d_in[6];
    const float* bk = (const float*)d_in[7];
    const float* Wv = (const float*)d_in[8];
    const float* bv = (const float*)d_in[9];
    float* out = (float*)d_out;

    short* ws  = (short*)d_ws;
    short* qb  = ws;
    short* kb  = qb  + NX;
    short* vb  = kb  + NX;
    short* wqb = vb  + NX;
    short* wkb = wqb + NW;
    short* wvb = wkb + NW;
    short* Q   = wvb + NW;
    short* K   = Q   + NX;
    short* Vp  = K   + NX;
    short* VT  = Vp  + NX;

    convert_all<<<15360, 256, 0, stream>>>(queries, keys, values, Wq, Wk, Wv,
                                           qb, kb, vb, wqb, wkb, wvb);
    gemm_bias_relu<<<dim3(8, 32, 3), 256, 0, stream>>>(qb, kb, vb, wqb, wkb, wvb,
                                                       bq, bk, bv, Q, K, Vp);
    transpose_v<<<dim3(32, 32), 256, 0, stream>>>(Vp, VT);
    attention<<<512, 128, 0, stream>>>(Q, K, VT, mask, queries, out);
}

// Round 7
// 203.289 us; speedup vs baseline: 1.1360x; 1.1360x over previous
//
#include <hip/hip_runtime.h>
#include <hip/hip_bf16.h>

#define DEV __device__ __forceinline__

typedef __attribute__((ext_vector_type(8))) short short8;
typedef __attribute__((ext_vector_type(4))) float f32x4;

#define MFMA16(a, b, c) __builtin_amdgcn_mfma_f32_16x16x32_bf16((a), (b), (c), 0, 0, 0)

static constexpr int B_ = 2, S_ = 2048, D_ = 1024, H_ = 16, HD_ = 64;
static constexpr long NX = (long)B_ * S_ * D_;   // 4194304
static constexpr long NW = (long)D_ * D_;        // 1048576

DEV short f2bf(float f) {
    __hip_bfloat16 h = __float2bfloat16(f);
    union { __hip_bfloat16 hh; short s; } u;
    u.hh = h;
    return u.s;
}

DEV float bf2f(short s) {
    union { float f; unsigned u; } x;
    x.u = ((unsigned)(unsigned short)s) << 16;
    return x.f;
}

// pack two f32 -> two bf16 (round-to-nearest-ish via +0x8000), 5 VALU ops
DEV unsigned pk2(float a, float b) {
    union { float f; unsigned u; } ua, ub;
    ua.f = a; ub.f = b;
    return ((ua.u + 0x8000u) >> 16) | ((ub.u + 0x8000u) & 0xffff0000u);
}

DEV short8 ld8(const short* p) { return *(const short8*)p; }

// async global->LDS, 16B per lane. LDS dest = wave-uniform base + lane*16.
DEV void gld16(const short* g, short* l) {
    __builtin_amdgcn_global_load_lds(
        (const __attribute__((address_space(1))) unsigned int*)g,
        (__attribute__((address_space(3))) unsigned int*)l, 16, 0, 0);
}

// ---------------------------------------------------------------- convert
__global__ __launch_bounds__(256) void convert_all(
    const float* __restrict__ q, const float* __restrict__ k, const float* __restrict__ v,
    const float* __restrict__ wq, const float* __restrict__ wk, const float* __restrict__ wv,
    short* __restrict__ qb, short* __restrict__ kb, short* __restrict__ vb,
    short* __restrict__ wqb, short* __restrict__ wkb, short* __restrict__ wvb) {
    long tid = (long)blockIdx.x * 256 + threadIdx.x;
    long e = tid * 4;
    const float* src; short* dst; long off;
    if      (e < NX)            { src = q;  dst = qb;  off = e; }
    else if (e < 2*NX)          { src = k;  dst = kb;  off = e - NX; }
    else if (e < 3*NX)          { src = v;  dst = vb;  off = e - 2*NX; }
    else if (e < 3*NX + NW)     { src = wq; dst = wqb; off = e - 3*NX; }
    else if (e < 3*NX + 2*NW)   { src = wk; dst = wkb; off = e - 3*NX - NW; }
    else                        { src = wv; dst = wvb; off = e - 3*NX - 2*NW; }
    float4 f = *(const float4*)(src + off);
    short4 o;
    o.x = f2bf(f.x); o.y = f2bf(f.y); o.z = f2bf(f.z); o.w = f2bf(f.w);
    *(short4*)(dst + off) = o;
}

// ---------------------------------------------------------------- GEMM
// m97 recipe + single-barrier async prefetch double-buffer.
__global__ __launch_bounds__(256) void gemm_bias_relu(
    const short* __restrict__ X0, const short* __restrict__ X1, const short* __restrict__ X2,
    const short* __restrict__ W0, const short* __restrict__ W1, const short* __restrict__ W2,
    const float* __restrict__ b0, const float* __restrict__ b1, const float* __restrict__ b2,
    short* __restrict__ O0, short* __restrict__ O1, short* __restrict__ O2) {
    __shared__ short As[2][128 * 32];
    __shared__ short Bs[2][128 * 32];

    const int z = blockIdx.z;
    const short* X   = (z == 0) ? X0 : (z == 1) ? X1 : X2;
    const short* W   = (z == 0) ? W0 : (z == 1) ? W1 : W2;
    const float* bia = (z == 0) ? b0 : (z == 1) ? b1 : b2;
    short*       Out = (z == 0) ? O0 : (z == 1) ? O1 : O2;

    const int tid  = threadIdx.x;
    const int wid  = tid >> 6;
    const int lane = tid & 63;
    const int id   = lane & 15;
    const int quad = lane >> 4;
    const int m0 = blockIdx.y * 128;
    const int n0 = blockIdx.x * 128;
    const int wm = (wid >> 1) * 64;
    const int wn = (wid & 1) * 64;

    const short* Ag0 = X + (long)(m0 + wid * 32 + (lane >> 2)) * D_ + (lane & 3) * 8;
    const short* Bg0 = W + (long)(n0 + wid * 32 + (lane >> 2)) * D_ + (lane & 3) * 8;
    const int offW = wid * 1024;  // wave's 32-row slab

    f32x4 acc[4][4] = {};

    gld16(Ag0,            &As[0][offW]);
    gld16(Ag0 + 16 * D_,  &As[0][offW + 512]);
    gld16(Bg0,            &Bs[0][offW]);
    gld16(Bg0 + 16 * D_,  &Bs[0][offW + 512]);

    for (int kk = 0; kk < D_; kk += 32) {
        const int cur = (kk >> 5) & 1;
        __syncthreads();
        if (kk + 32 < D_) {
            const int nxt = cur ^ 1;
            gld16(Ag0 + kk + 32,            &As[nxt][offW]);
            gld16(Ag0 + 16 * D_ + kk + 32,  &As[nxt][offW + 512]);
            gld16(Bg0 + kk + 32,            &Bs[nxt][offW]);
            gld16(Bg0 + 16 * D_ + kk + 32,  &Bs[nxt][offW + 512]);
        }

        short8 af[4], bf[4];
#pragma unroll
        for (int i = 0; i < 4; i++) af[i] = ld8(&As[cur][(wm + 16*i + id) * 32 + quad * 8]);
#pragma unroll
        for (int j = 0; j < 4; j++) bf[j] = ld8(&Bs[cur][(wn + 16*j + id) * 32 + quad * 8]);
#pragma unroll
        for (int i = 0; i < 4; i++)
#pragma unroll
            for (int j = 0; j < 4; j++)
                acc[i][j] = MFMA16(af[i], bf[j], acc[i][j]);
    }

#pragma unroll
    for (int j = 0; j < 4; j++) {
        int col = n0 + wn + 16*j + id;
        float bj = bia[col];
#pragma unroll
        for (int i = 0; i < 4; i++) {
#pragma unroll
            for (int r = 0; r < 4; r++) {
                int row = m0 + wm + 16*i + quad*4 + r;
                float val = fmaxf(acc[i][j][r] + bj, 0.f);
                Out[(long)row * D_ + col] = f2bf(val);
            }
        }
    }
}

// ---------------------------------------------------------------- V transpose
__global__ __launch_bounds__(256) void transpose_v(const short* __restrict__ Vp,
                                                   short* __restrict__ VT) {
    __shared__ short tile[64 * 64];
    const int bh = blockIdx.y;
    const int b = bh >> 4, h = bh & 15;
    const int s0 = blockIdx.x * 64;
    const int t = threadIdx.x;
#pragma unroll
    for (int it = 0; it < 2; it++) {
        int row = (t >> 3) + 32 * it;
        int u   = t & 7;
        short8 d = ld8(Vp + (long)(b * S_ + s0 + row) * D_ + h * HD_ + u * 8);
        *(short8*)(&tile[row * 64 + (u ^ ((row >> 3) & 7)) * 8]) = d;
    }
    __syncthreads();
#pragma unroll
    for (int it = 0; it < 2; it++) {
        int e  = (t >> 3) + 32 * it;
        int sb = (t & 7) * 8;
        short8 o;
#pragma unroll
        for (int u = 0; u < 8; u++) {
            int row = sb + u;
            o[u] = tile[row * 64 + (((e >> 3) ^ ((row >> 3) & 7)) * 8) + (e & 7)];
        }
        *(short8*)(VT + ((long)bh * HD_ + e) * S_ + s0 + sb) = o;
    }
}

// ---------------------------------------------------------------- attention
// R5 structure (4 waves/block, 32 q/wave, async-prefetch dbuf staging) +
// XCD swizzle (all 16 q-tiles of one (b,h) on one XCD -> K/V stays in that
// XCD's L2) + cheap bit-packed bf16 P-pack.
__global__ __launch_bounds__(256, 2) void attention(
    const short* __restrict__ Qb, const short* __restrict__ Kb,
    const short* __restrict__ VT, const int* __restrict__ mask,
    const float* __restrict__ queries, float* __restrict__ out) {
    __shared__ short Ks[2][64 * 64];        // [buf][key][dim], swizzled units
    __shared__ short Vs[2][64 * 64];        // [buf][dim][key], swizzled units
    __shared__ short pl[4][2 * 16 * 72];    // [wave][group][16 q][72]

    const int tid  = threadIdx.x;
    const int wid  = tid >> 6;
    const int lane = tid & 63;
    const int id   = lane & 15;
    const int quad = lane >> 4;

    // XCD swizzle: xcd = bid&7 -> bh = xcd + 8*(w&3), qt = w>>2.
    // All 16 q-tiles of a (b,h) share bid%8, i.e. (heuristically) one XCD.
    const int bid = blockIdx.x;          // 512
    const int w   = bid >> 3;
    const int bh  = (bid & 7) + 8 * (w & 3);
    const int qt  = w >> 2;              // 0..15
    const int b   = bh >> 4;
    const int h   = bh & 15;
    const int q0  = qt * 128 + wid * 32;

    // Q fragments (B-operand), per group, pre-scaled by 1/8 (0 if masked)
    short8 qf[2][2];
#pragma unroll
    for (int g = 0; g < 2; g++) {
        const short* qbase = Qb + (long)(b * S_ + q0 + g * 16 + id) * D_ + h * HD_ + quad * 8;
        short8 f0 = ld8(qbase);
        short8 f1 = ld8(qbase + 32);
        const float qsc = mask[b * S_ + q0 + g * 16 + id] ? 0.125f : 0.f;
#pragma unroll
        for (int i = 0; i < 8; i++) {
            f0[i] = f2bf(bf2f(f0[i]) * qsc);
            f1[i] = f2bf(bf2f(f1[i]) * qsc);
        }
        qf[g][0] = f0; qf[g][1] = f1;
    }

    // staging: row r = wid*16 + (lane>>3) (+8 for 2nd instr),
    // unit u = (lane&7) ^ (r&7)   ((r+8)&7 == r&7)
    const int srow = wid * 16 + (lane >> 3);
    const int su   = (lane & 7) ^ (srow & 7);
    const short* kg0 = Kb + ((long)b * S_ + srow) * D_ + h * HD_ + su * 8;
    const short* vg0 = VT + (((long)(b * H_ + h) * HD_) + srow) * S_ + su * 8;
    short* plw = pl[wid];

    const int swz = id & 7;  // reader-side swizzle key

    float l4[2][4] = {};
    f32x4 o[2][4] = {};

    gld16(kg0,            &Ks[0][wid * 1024]);
    gld16(kg0 + 8 * D_,   &Ks[0][wid * 1024 + 512]);
    gld16(vg0,            &Vs[0][wid * 1024]);
    gld16(vg0 + 8 * S_,   &Vs[0][wid * 1024 + 512]);

    for (int c0 = 0; c0 < S_; c0 += 64) {
        const int cur = (c0 >> 6) & 1;
        __syncthreads();  // drains stage(c0), issued one full chunk earlier
        if (c0 + 64 < S_) {
            const int nxt = cur ^ 1;
            const long cg = (long)(c0 + 64);
            gld16(kg0 + cg * D_,           &Ks[nxt][wid * 1024]);
            gld16(kg0 + cg * D_ + 8 * D_,  &Ks[nxt][wid * 1024 + 512]);
            gld16(vg0 + cg,                &Vs[nxt][wid * 1024]);
            gld16(vg0 + cg + 8 * S_,       &Vs[nxt][wid * 1024 + 512]);
        }

        // ---- S^T = K·Q^T (both query groups share A-frags)
        f32x4 s[2][4];
#pragma unroll
        for (int g = 0; g < 2; g++)
#pragma unroll
            for (int t = 0; t < 4; t++) s[g][t] = (f32x4){0.f, 0.f, 0.f, 0.f};
#pragma unroll
        for (int t = 0; t < 4; t++) {
            short8 a0 = ld8(&Ks[cur][(16*t + id) * 64 + ((quad    ) ^ swz) * 8]);
            short8 a1 = ld8(&Ks[cur][(16*t + id) * 64 + ((quad ^ 4) ^ swz) * 8]);
            s[0][t] = MFMA16(a0, qf[0][0], s[0][t]);
            s[0][t] = MFMA16(a1, qf[0][1], s[0][t]);
            s[1][t] = MFMA16(a0, qf[1][0], s[1][t]);
            s[1][t] = MFMA16(a1, qf[1][1], s[1][t]);
        }

        // ---- p = exp(s), accumulate l, bit-packed P^T to LDS
#pragma unroll
        for (int g = 0; g < 2; g++) {
            short* plg = plw + g * (16 * 72);
#pragma unroll
            for (int t = 0; t < 4; t++) {
                float p0 = __expf(s[g][t][0]);
                float p1 = __expf(s[g][t][1]);
                float p2 = __expf(s[g][t][2]);
                float p3 = __expf(s[g][t][3]);
                l4[g][0] += p0; l4[g][1] += p1; l4[g][2] += p2; l4[g][3] += p3;
                uint2 w2;
                w2.x = pk2(p0, p1);
                w2.y = pk2(p2, p3);
                *(uint2*)(&plg[id * 72 + 16 * t + quad * 4]) = w2;
            }
        }
        short8 pf[2][2];
#pragma unroll
        for (int g = 0; g < 2; g++) {
            short* plg = plw + g * (16 * 72);
            pf[g][0] = ld8(&plg[id * 72 + quad * 8]);
            pf[g][1] = ld8(&plg[id * 72 + 32 + quad * 8]);
        }

        // ---- O^T += V^T·P^T (A-frags shared by both groups)
#pragma unroll
        for (int j2 = 0; j2 < 4; j2++) {
#pragma unroll
            for (int kh = 0; kh < 2; kh++) {
                short8 va = ld8(&Vs[cur][(16*j2 + id) * 64 + (((kh << 2) + quad) ^ swz) * 8]);
                o[0][j2] = MFMA16(va, pf[0][kh], o[0][j2]);
                o[1][j2] = MFMA16(va, pf[1][kh], o[1][j2]);
            }
        }
    }

    // ---- epilogue
    const long obase = (long)b * (S_ * D_) + (long)h * (HD_ * S_);
#pragma unroll
    for (int g = 0; g < 2; g++) {
        float l = l4[g][0] + l4[g][1] + l4[g][2] + l4[g][3];
        l += __shfl_xor(l, 16);
        l += __shfl_xor(l, 32);
        const float linv = 1.f / l;
#pragma unroll
        for (int j2 = 0; j2 < 4; j2++) {
#pragma unroll
            for (int r = 0; r < 4; r++) {
                int dim = 16 * j2 + quad * 4 + r;
                long idx = obase + (long)dim * S_ + q0 + g * 16 + id;
                out[idx] = o[g][j2][r] * linv + queries[idx];
            }
        }
    }
}

// ---------------------------------------------------------------- launch
extern "C" void kernel_launch(void* const* d_in, const int* in_sizes, int n_in,
                              void* d_out, int out_size, void* d_ws, size_t ws_size,
                              hipStream_t stream) {
    const float* queries = (const float*)d_in[0];
    const float* keys    = (const float*)d_in[1];
    const float* values  = (const float*)d_in[2];
    const int*   mask    = (const int*)d_in[3];
    const float* Wq = (const float*)d_in[4];
    const float* bq = (const float*)d_in[5];
    const float* Wk = (const float*)d_in[6];
    const float* bk = (const float*)d_in[7];
    const float* Wv = (const float*)d_in[8];
    const float* bv = (const float*)d_in[9];
    float* out = (float*)d_out;

    short* ws  = (short*)d_ws;
    short* qb  = ws;
    short* kb  = qb  + NX;
    short* vb  = kb  + NX;
    short* wqb = vb  + NX;
    short* wkb = wqb + NW;
    short* wvb = wkb + NW;
    short* Q   = wvb + NW;
    short* K   = Q   + NX;
    short* Vp  = K   + NX;
    short* VT  = Vp  + NX;

    convert_all<<<15360, 256, 0, stream>>>(queries, keys, values, Wq, Wk, Wv,
                                           qb, kb, vb, wqb, wkb, wvb);
    gemm_bias_relu<<<dim3(8, 32, 3), 256, 0, stream>>>(qb, kb, vb, wqb, wkb, wvb,
                                                       bq, bk, bv, Q, K, Vp);
    transpose_v<<<dim3(32, 32), 256, 0, stream>>>(Vp, VT);
    attention<<<512, 256, 0, stream>>>(Q, K, VT, mask, queries, out);
}